// Round 4
// baseline (257.774 us; speedup 1.0000x reference)
//
#include <hip/hip_runtime.h>
#include <hip/hip_bf16.h>

using bf16 = __hip_bfloat16;
using bf16x8 = __attribute__((ext_vector_type(8))) short;   // 8 bf16 = 4 VGPRs (MFMA A/B frag)
using f32x4  = __attribute__((ext_vector_type(4))) float;   // MFMA C/D frag (native vector)

#define B_    16
#define HIM   56
#define WIM   56
#define HD    512
#define NHEAD 8
#define DH    64
#define NTOK  (HIM*WIM)      // 3136
#define M_    (B_*NTOK)      // 50176
#define K49   49

// ---- async global->LDS, 16B per lane; LDS dest = wave-uniform base (+lane*16 by HW) ----
__device__ __forceinline__ void gload_lds16(const void* g, void* l) {
  __builtin_amdgcn_global_load_lds(
      (__attribute__((address_space(1))) const void*)g,
      (__attribute__((address_space(3))) void*)l, 16, 0, 0);
}

// ---------------- kernel: fp32 -> bf16 convert (vectorized, 8 elems/thread) ----------------
__global__ __launch_bounds__(256) void cvt_x_kernel(const float* __restrict__ in,
                                                    bf16* __restrict__ out) {
  size_t i = ((size_t)blockIdx.x * 256 + threadIdx.x) * 8;
  float4 a = *(const float4*)(in + i);
  float4 b = *(const float4*)(in + i + 4);
  union { uint4 v; bf16 h[8]; } o;
  o.h[0] = __float2bfloat16(a.x); o.h[1] = __float2bfloat16(a.y);
  o.h[2] = __float2bfloat16(a.z); o.h[3] = __float2bfloat16(a.w);
  o.h[4] = __float2bfloat16(b.x); o.h[5] = __float2bfloat16(b.y);
  o.h[6] = __float2bfloat16(b.z); o.h[7] = __float2bfloat16(b.w);
  *(uint4*)(out + i) = o.v;
}

// ---------------- kernel: W (K x N) -> Wt (N x K) bf16 ----------------
__global__ __launch_bounds__(256) void cvt_transpose_kernel(const float* __restrict__ in,
                                                            bf16* __restrict__ out,
                                                            int K, int N) {
  int idx = blockIdx.x * 256 + threadIdx.x;   // grid covers K*N exactly
  int k = idx / N, n = idx - k * N;
  out[(size_t)n * K + k] = __float2bfloat16(in[idx]);
}

// ============================================================================
// 256x256-tile 8-phase GEMM (T2+T3+T4+T5 port): C(MxN) = A(MxK) * Bt(NxK)^T
// 512 threads = 8 waves (2M x 4N); per-wave output 128x64.
// K processed in kslices of 32; LDS ring: 4 slots x (A 256x32 + B 256x32).
// Stage lookahead 3 kslices (6 halves, 12 loads); vmcnt(8) steady state.
// XOR swizzle slot^((row>>1)&3): pre-swizzled global src, linear LDS dest,
// same involution on ds_read (rounds 1-2: SQ_LDS_BANK_CONFLICT == 0).
// MFMA operands SWAPPED (mfma(b,a)) so each lane holds 4 consecutive C-cols
// of one row -> packed 8B/16B epilogue stores (kills the 2B-scatter write
// amplification seen in round 2: WRITE 289MB vs 154MB ideal).
// ============================================================================
template<bool OUT_BF16, bool BIAS>
__global__ __launch_bounds__(512, 2) void gemm256_kernel(
    const bf16* __restrict__ A,    // M x K row-major
    const bf16* __restrict__ Bt,   // N x K row-major
    void* __restrict__ Cp,
    const float* __restrict__ bias,
    int M, int N, int K, int NBX)
{
  __shared__ alignas(16) bf16 lds[2][4][256 * 32];   // [A/B][slot][row*32+col] = 128 KiB
  const int tid  = threadIdx.x;
  const int lane = tid & 63, wid = tid >> 6;
  const int l15  = lane & 15, kq = lane >> 4;
  const int wm   = wid >> 2,  wn = wid & 3;
  // XCD-aware swizzle (gridDim.x % 8 == 0 for both launches)
  const int cpx = gridDim.x >> 3;
  const int wg  = (blockIdx.x & 7) * cpx + (blockIdx.x >> 3);
  const int by  = wg / NBX, bx = wg - by * NBX;
  const long arow0 = (long)by * 256;
  const long bcol0 = (long)bx * 256;

  // stage one half-tile (A or B of kslice j): 256 rows x 32 cols = 16 KB, 2 loads/thread
  auto stageHalf = [&](int ab, int j) {
    const bf16* g = (ab ? Bt + bcol0 * K : A + arow0 * K) + j * 32;
    bf16* lbase = &lds[ab][j & 3][0];
#pragma unroll
    for (int c = 0; c < 2; ++c) {
      int s   = c * 512 + tid;          // 16B-slot id (1024 per half)
      int row = s >> 2, sl = s & 3;
      int gs  = sl ^ ((row >> 1) & 3);  // pre-swizzled global source slot
      gload_lds16((const char*)(g + (long)row * K) + gs * 16,
                  lbase + (c * 512 + wid * 64) * 8);   // wave-uniform dest
    }
  };

  f32x4 acc[8][4] = {};   // [mt][nt]: C rows wm*128+mt*16+l15, cols wn*64+nt*16+kq*4+r

#define KSLICE(J, VM, DOSTAGE) {                                                        \
    const int sl4 = (J) & 3;                                                            \
    asm volatile("s_waitcnt vmcnt(" #VM ")" ::: "memory");                              \
    __builtin_amdgcn_s_barrier();                                                       \
    __builtin_amdgcn_sched_barrier(0);                                                  \
    bf16x8 af[8], bf[2];                                                                \
    _Pragma("unroll")                                                                   \
    for (int mt = 0; mt < 8; ++mt) {                                                    \
      int row = wm * 128 + mt * 16 + l15;                                               \
      af[mt] = *(const bf16x8*)&lds[0][sl4][row * 32 + ((kq ^ ((row >> 1) & 3)) << 3)]; \
    }                                                                                   \
    _Pragma("unroll")                                                                   \
    for (int nt = 0; nt < 2; ++nt) {                                                    \
      int row = wn * 64 + nt * 16 + l15;                                                \
      bf[nt] = *(const bf16x8*)&lds[1][sl4][row * 32 + ((kq ^ ((row >> 1) & 3)) << 3)]; \
    }                                                                                   \
    if (DOSTAGE) stageHalf(0, (J) + 3);                                                 \
    asm volatile("s_waitcnt lgkmcnt(0)" ::: "memory");                                  \
    __builtin_amdgcn_sched_barrier(0);                                                  \
    __builtin_amdgcn_s_setprio(1);                                                      \
    _Pragma("unroll")                                                                   \
    for (int mt = 0; mt < 8; ++mt)                                                      \
      _Pragma("unroll")                                                                 \
      for (int nt = 0; nt < 2; ++nt)                                                    \
        acc[mt][nt] = __builtin_amdgcn_mfma_f32_16x16x32_bf16(bf[nt], af[mt],           \
                                                              acc[mt][nt], 0, 0, 0);    \
    __builtin_amdgcn_s_setprio(0);                                                      \
    __builtin_amdgcn_s_barrier();                                                       \
    bf16x8 bg[2];                                                                       \
    _Pragma("unroll")                                                                   \
    for (int nt = 0; nt < 2; ++nt) {                                                    \
      int row = wn * 64 + (nt + 2) * 16 + l15;                                          \
      bg[nt] = *(const bf16x8*)&lds[1][sl4][row * 32 + ((kq ^ ((row >> 1) & 3)) << 3)]; \
    }                                                                                   \
    if (DOSTAGE) stageHalf(1, (J) + 3);                                                 \
    asm volatile("s_waitcnt lgkmcnt(0)" ::: "memory");                                  \
    __builtin_amdgcn_sched_barrier(0);                                                  \
    __builtin_amdgcn_s_setprio(1);                                                      \
    _Pragma("unroll")                                                                   \
    for (int mt = 0; mt < 8; ++mt)                                                      \
      _Pragma("unroll")                                                                 \
      for (int nt = 0; nt < 2; ++nt)                                                    \
        acc[mt][nt + 2] = __builtin_amdgcn_mfma_f32_16x16x32_bf16(bg[nt], af[mt],       \
                                                              acc[mt][nt + 2], 0, 0, 0);\
    __builtin_amdgcn_s_setprio(0);                                                      \
    __builtin_amdgcn_s_barrier();                                                       \
  }

  // prologue: 3 kslices in flight (A0,B0,A1,B1,A2,B2 = 12 loads)
  stageHalf(0, 0); stageHalf(1, 0);
  stageHalf(0, 1); stageHalf(1, 1);
  stageHalf(0, 2); stageHalf(1, 2);

  const int NK = K >> 5;    // 16 kslices at K=512
#pragma unroll 1
  for (int j = 0; j < NK - 3; ++j) KSLICE(j, 8, true);
  KSLICE(NK - 3, 8, false);   // staged halves A/B(NK-1) still landing
  KSLICE(NK - 2, 4, false);
  KSLICE(NK - 1, 0, false);
#undef KSLICE

  // epilogue: lane holds rows crow0+mt*16+l15, cols ccol0+nt*16+kq*4+{0..3}
  const long crow0 = arow0 + wm * 128;
  const long ccol0 = bcol0 + wn * 64 + kq * 4;
#pragma unroll
  for (int mt = 0; mt < 8; ++mt) {
    long row = crow0 + mt * 16 + l15;
#pragma unroll
    for (int nt = 0; nt < 4; ++nt) {
      long col = ccol0 + nt * 16;
      if (OUT_BF16) {
        union { unsigned long long u; unsigned short h[4]; } pk;
#pragma unroll
        for (int r = 0; r < 4; ++r) {
          bf16 hh = __float2bfloat16(acc[mt][nt][r]);
          pk.h[r] = *(unsigned short*)&hh;
        }
        __builtin_nontemporal_store(pk.u,
            (unsigned long long*)((bf16*)Cp + row * N + col));
      } else {
        f32x4 o = acc[mt][nt];
        if (BIAS) {
          o[0] += bias[col];     o[1] += bias[col + 1];
          o[2] += bias[col + 2]; o[3] += bias[col + 3];
        }
        __builtin_nontemporal_store(o, (f32x4*)((float*)Cp + row * N + col));
      }
    }
  }
}

// ---------------- kernel: windowed attention, one WG per (b, window p, head g) ------------
// qkv: [B][3136][1536] bf16 (cols: q 0-511 | k 512-1023 | v 1024-1535), head g slice = g*64
// rb : [8][49][49] fp32 ; outa: [B][3136][512] bf16
__global__ __launch_bounds__(256) void attn_win_kernel(
    const bf16* __restrict__ qkv, const float* __restrict__ rb, bf16* __restrict__ outa)
{
  __shared__ alignas(16) bf16 Qs[64 * 72];  // [token][chan], stride 72 (144B -> 2-way free)
  __shared__ alignas(16) bf16 Ks[64 * 72];
  __shared__ alignas(16) bf16 Vt[64 * 72];  // transposed: [chan][token]
  __shared__ alignas(16) bf16 Ps[64 * 72];  // probabilities [q][k]
  const int tid = threadIdx.x, lane = tid & 63, wid = tid >> 6;
  const int p = blockIdx.x, g = blockIdx.y, b = blockIdx.z;
  const int sh = p >> 3, sw = p & 7;
  const size_t nb = (size_t)b * NTOK;
  const int c8 = (tid & 7) * 8;

  // stage Q,K row-major + V transposed; zero-fill pad tokens 49..63
#pragma unroll
  for (int it = 0; it < 2; ++it) {
    int t = (tid >> 3) + it * 32;
    uint4 vq = {0, 0, 0, 0}, vk = vq, vv = vq;
    if (t < K49) {
      int ph = t / 7, pw = t - ph * 7;
      int n = (sh * 7 + ph) * WIM + sw * 7 + pw;
      const bf16* src = qkv + (nb + n) * 1536 + g * 64 + c8;
      vq = *(const uint4*)(src);
      vk = *(const uint4*)(src + 512);
      vv = *(const uint4*)(src + 1024);
    }
    *(uint4*)&Qs[t * 72 + c8] = vq;
    *(uint4*)&Ks[t * 72 + c8] = vk;
    union { uint4 u; unsigned short s[8]; } uv; uv.u = vv;
    unsigned short* vt16 = (unsigned short*)Vt;
#pragma unroll
    for (int e = 0; e < 8; ++e) vt16[(c8 + e) * 72 + t] = uv.s[e];
  }
  __syncthreads();

  const int l15 = lane & 15, kq = lane >> 4;
  // ---- S = Q K^T (wave w owns q rows 16w..16w+15; 4 col tiles) ----
  bf16x8 aq[2];
#pragma unroll
  for (int kk = 0; kk < 2; ++kk)
    aq[kk] = *(const bf16x8*)&Qs[(wid * 16 + l15) * 72 + kk * 32 + kq * 8];
  float sv[4][4];   // [ct][r]
#pragma unroll
  for (int ct = 0; ct < 4; ++ct) {
    f32x4 acc = {0.f, 0.f, 0.f, 0.f};
#pragma unroll
    for (int kk = 0; kk < 2; ++kk) {
      bf16x8 bk = *(const bf16x8*)&Ks[(ct * 16 + l15) * 72 + kk * 32 + kq * 8];
      acc = __builtin_amdgcn_mfma_f32_16x16x32_bf16(aq[kk], bk, acc, 0, 0, 0);
    }
    int kcol = ct * 16 + l15;
#pragma unroll
    for (int r = 0; r < 4; ++r) {
      int q = wid * 16 + kq * 4 + r;
      float bias = (q < K49 && kcol < K49) ? rb[((size_t)g * K49 + q) * K49 + kcol] : 0.f;
      float v = (acc[r] + bias) * 0.125f;          // (S + rel_bias) * dh^-0.5
      sv[ct][r] = (kcol < K49) ? v : -1e30f;       // mask pad keys
    }
  }
  // ---- softmax over keys (row q lives in the 16 lanes sharing kq) ----
#pragma unroll
  for (int r = 0; r < 4; ++r) {
    float m = fmaxf(fmaxf(sv[0][r], sv[1][r]), fmaxf(sv[2][r], sv[3][r]));
#pragma unroll
    for (int d = 1; d < 16; d <<= 1) m = fmaxf(m, __shfl_xor(m, d));
    float e0 = __expf(sv[0][r] - m), e1 = __expf(sv[1][r] - m);
    float e2 = __expf(sv[2][r] - m), e3 = __expf(sv[3][r] - m);
    float s = e0 + e1 + e2 + e3;
#pragma unroll
    for (int d = 1; d < 16; d <<= 1) s += __shfl_xor(s, d);
    float inv = 1.0f / s;
    int q = wid * 16 + kq * 4 + r;
    Ps[q * 72 +  0 + l15] = __float2bfloat16(e0 * inv);
    Ps[q * 72 + 16 + l15] = __float2bfloat16(e1 * inv);
    Ps[q * 72 + 32 + l15] = __float2bfloat16(e2 * inv);
    Ps[q * 72 + 48 + l15] = __float2bfloat16(e3 * inv);
  }
  __syncthreads();
  // ---- O = P V ----
  bf16x8 ap[2];
#pragma unroll
  for (int kk = 0; kk < 2; ++kk)
    ap[kk] = *(const bf16x8*)&Ps[(wid * 16 + l15) * 72 + kk * 32 + kq * 8];
#pragma unroll
  for (int ct = 0; ct < 4; ++ct) {
    f32x4 acc = {0.f, 0.f, 0.f, 0.f};
#pragma unroll
    for (int kk = 0; kk < 2; ++kk) {
      bf16x8 bv = *(const bf16x8*)&Vt[(ct * 16 + l15) * 72 + kk * 32 + kq * 8];
      acc = __builtin_amdgcn_mfma_f32_16x16x32_bf16(ap[kk], bv, acc, 0, 0, 0);
    }
#pragma unroll
    for (int r = 0; r < 4; ++r) {
      int q = wid * 16 + kq * 4 + r;
      if (q < K49) {
        int ph = q / 7, pw = q - ph * 7;
        int n = (sh * 7 + ph) * WIM + sw * 7 + pw;
        outa[(nb + n) * HD + g * 64 + ct * 16 + l15] = __float2bfloat16(acc[r]);
      }
    }
  }
}

// ---------------- launch ----------------
extern "C" void kernel_launch(void* const* d_in, const int* in_sizes, int n_in,
                              void* d_out, int out_size, void* d_ws, size_t ws_size,
                              hipStream_t stream) {
  (void)in_sizes; (void)n_in; (void)out_size;
  const float* x     = (const float*)d_in[0];
  // d_in[1] = mask: all-False with zero padding (56 % 7 == 0) -> no-op, skipped
  const float* wqkv  = (const float*)d_in[2];
  const float* wproj = (const float*)d_in[3];
  const float* bproj = (const float*)d_in[4];
  const float* rb    = (const float*)d_in[5];
  // d_in[6], d_in[7] = H, W (56, 56) constants

  // workspace layout (207,618,048 bytes total)
  char* ws = (char*)d_ws;
  bf16* x_bf    = (bf16*)(ws);              // 51,380,224 B ; reused as attnout after GEMM1
  bf16* wqkv_t  = (bf16*)(ws + 51380224);   //  1,572,864 B
  bf16* wproj_t = (bf16*)(ws + 52953088);   //    524,288 B
  bf16* qkv     = (bf16*)(ws + 53477376);   // 154,140,672 B
  bf16* attno   = x_bf;
  float* out    = (float*)d_out;
  if (ws_size < 207618048) return;  // fail visibly rather than corrupt

  cvt_x_kernel<<<dim3(12544), 256, 0, stream>>>(x, x_bf);                       // 50176*512/8/256
  cvt_transpose_kernel<<<dim3(3072), 256, 0, stream>>>(wqkv, wqkv_t, 512, 1536);
  cvt_transpose_kernel<<<dim3(1024), 256, 0, stream>>>(wproj, wproj_t, 512, 512);
  // GEMM1: 196 M-tiles x 6 N-tiles = 1176 blocks (1176 % 8 == 0)
  gemm256_kernel<true, false><<<dim3(1176), 512, 0, stream>>>(
      x_bf, wqkv_t, (void*)qkv, nullptr, M_, 1536, 512, 6);
  attn_win_kernel<<<dim3(64, NHEAD, B_), 256, 0, stream>>>(qkv, rb, attno);
  // GEMM2: 196 x 2 = 392 blocks (392 % 8 == 0)
  gemm256_kernel<false, true><<<dim3(392), 512, 0, stream>>>(
      attno, wproj_t, (void*)out, bproj, M_, 512, 512, 2);
}

// Round 5
// 256.398 us; speedup vs baseline: 1.0054x; 1.0054x over previous
//
#include <hip/hip_runtime.h>
#include <hip/hip_bf16.h>

using bf16 = __hip_bfloat16;
using bf16x8 = __attribute__((ext_vector_type(8))) short;   // 8 bf16 = 4 VGPRs (MFMA A/B frag)
using f32x4  = __attribute__((ext_vector_type(4))) float;   // MFMA C/D frag (native vector)

#define B_    16
#define HIM   56
#define WIM   56
#define HD    512
#define NHEAD 8
#define DH    64
#define NTOK  (HIM*WIM)      // 3136
#define M_    (B_*NTOK)      // 50176
#define K49   49

// ---- async global->LDS, 16B per lane; LDS dest = wave-uniform base (+lane*16 by HW) ----
__device__ __forceinline__ void gload_lds16(const void* g, void* l) {
  __builtin_amdgcn_global_load_lds(
      (__attribute__((address_space(1))) const void*)g,
      (__attribute__((address_space(3))) void*)l, 16, 0, 0);
}

// ---------------- kernel: fp32 -> bf16 convert (vectorized, 8 elems/thread) ----------------
__global__ __launch_bounds__(256) void cvt_x_kernel(const float* __restrict__ in,
                                                    bf16* __restrict__ out) {
  size_t i = ((size_t)blockIdx.x * 256 + threadIdx.x) * 8;
  float4 a = *(const float4*)(in + i);
  float4 b = *(const float4*)(in + i + 4);
  union { uint4 v; bf16 h[8]; } o;
  o.h[0] = __float2bfloat16(a.x); o.h[1] = __float2bfloat16(a.y);
  o.h[2] = __float2bfloat16(a.z); o.h[3] = __float2bfloat16(a.w);
  o.h[4] = __float2bfloat16(b.x); o.h[5] = __float2bfloat16(b.y);
  o.h[6] = __float2bfloat16(b.z); o.h[7] = __float2bfloat16(b.w);
  *(uint4*)(out + i) = o.v;
}

// ---------------- kernel: W (K x N) -> Wt (N x K) bf16 ----------------
__global__ __launch_bounds__(256) void cvt_transpose_kernel(const float* __restrict__ in,
                                                            bf16* __restrict__ out,
                                                            int K, int N) {
  int idx = blockIdx.x * 256 + threadIdx.x;   // grid covers K*N exactly
  int k = idx / N, n = idx - k * N;
  out[(size_t)n * K + k] = __float2bfloat16(in[idx]);
}

// ============================================================================
// 256x256-tile GEMM, 4-slot LDS ring, counted vmcnt, ONE barrier per kslice.
// C(MxN) = A(MxK) * Bt(NxK)^T, K=512 compile-time (16 kslices of 32).
// 512 threads = 8 waves (2M x 4N); per-wave output 128x64.
// Ring: slot j&3; stage(j+3) issued after top-of-j barrier -> overwrites the
// slot last read at j-1, which every wave finished before that barrier.
// Correctness of vmcnt: per-wave vmcnt(8) BEFORE the barrier => after the
// barrier, every wave's kslice-j loads have landed.
// NO lgkmcnt/sched_barrier walls: compiler emits fine-grained lgkmcnt
// interleaving of ds_read and MFMA (m97 finding; m141: pinning = -42%).
// XOR swizzle slot^((row>>1)&3) on 16B slots: pre-swizzled global src,
// linear LDS dest, same involution on ds_read (rounds 1-4: 0 conflicts).
// MFMA operands swapped (mfma(b,a)): lane holds 4 consecutive C-cols of one
// row -> packed 8B/16B epilogue stores (round 4: WRITE = ideal).
// ============================================================================
template<int N, bool OUT_BF16, bool BIAS>
__global__ __launch_bounds__(512, 2) void gemm256_kernel(
    const bf16* __restrict__ A,    // M x 512 row-major
    const bf16* __restrict__ Bt,   // N x 512 row-major
    void* __restrict__ Cp,
    const float* __restrict__ bias,
    int NBX)
{
  constexpr int K  = 512;
  constexpr int NK = K / 32;       // 16 kslices
  __shared__ alignas(16) bf16 lds[2][4][256 * 32];   // [A/B][slot][row*32+col] = 128 KiB
  const int tid  = threadIdx.x;
  const int lane = tid & 63, wid = tid >> 6;
  const int l15  = lane & 15, kq = lane >> 4;
  const int wm   = wid >> 2,  wn = wid & 3;
  // XCD-aware swizzle (gridDim.x % 8 == 0 for both launches)
  const int cpx = gridDim.x >> 3;
  const int wg  = (blockIdx.x & 7) * cpx + (blockIdx.x >> 3);
  const int by  = wg / NBX, bx = wg - by * NBX;
  const long arow0 = (long)by * 256;
  const long bcol0 = (long)bx * 256;

  // stage one half-tile (A or B of kslice j): 256 rows x 32 cols = 16 KB, 2 loads/thread
  auto stageHalf = [&](int ab, int j) {
    const bf16* g = (ab ? Bt + bcol0 * K : A + arow0 * K) + j * 32;
    bf16* lbase = &lds[ab][j & 3][0];
#pragma unroll
    for (int c = 0; c < 2; ++c) {
      int s   = c * 512 + tid;          // 16B-slot id (1024 per half)
      int row = s >> 2, sl = s & 3;
      int gs  = sl ^ ((row >> 1) & 3);  // pre-swizzled global source slot
      gload_lds16((const char*)(g + (long)row * K) + gs * 16,
                  lbase + (c * 512 + wid * 64) * 8);   // wave-uniform dest
    }
  };

  f32x4 acc[8][4] = {};   // [mt][nt]: C rows wm*128+mt*16+l15, cols wn*64+nt*16+kq*4+r

  // one kslice: SL is compile-time (ring slot), VMSTR a literal string
#define KSLICE(SL, VMSTR, DOSTAGE, JSTAGE) {                                            \
    asm volatile("s_waitcnt vmcnt(" VMSTR ")" ::: "memory");                            \
    __builtin_amdgcn_s_barrier();                                                       \
    bf16x8 af[8], bb[4];                                                                \
    _Pragma("unroll")                                                                   \
    for (int mt = 0; mt < 8; ++mt) {                                                    \
      int row = wm * 128 + mt * 16 + l15;                                               \
      af[mt] = *(const bf16x8*)&lds[0][SL][row * 32 + ((kq ^ ((row >> 1) & 3)) << 3)];  \
    }                                                                                   \
    _Pragma("unroll")                                                                   \
    for (int nt = 0; nt < 4; ++nt) {                                                    \
      int row = wn * 64 + nt * 16 + l15;                                                \
      bb[nt] = *(const bf16x8*)&lds[1][SL][row * 32 + ((kq ^ ((row >> 1) & 3)) << 3)];  \
    }                                                                                   \
    if (DOSTAGE) { stageHalf(0, JSTAGE); stageHalf(1, JSTAGE); }                        \
    __builtin_amdgcn_s_setprio(1);                                                      \
    _Pragma("unroll")                                                                   \
    for (int mt = 0; mt < 8; ++mt)                                                      \
      _Pragma("unroll")                                                                 \
      for (int nt = 0; nt < 4; ++nt)                                                    \
        acc[mt][nt] = __builtin_amdgcn_mfma_f32_16x16x32_bf16(bb[nt], af[mt],           \
                                                              acc[mt][nt], 0, 0, 0);    \
    __builtin_amdgcn_s_setprio(0);                                                      \
  }

  // prologue: 3 kslices in flight (12 loads/wave)
  stageHalf(0, 0); stageHalf(1, 0);
  stageHalf(0, 1); stageHalf(1, 1);
  stageHalf(0, 2); stageHalf(1, 2);

  // steady state: kslices 0..11 in unroll-4 groups (slot = compile-time 0..3)
#pragma unroll 1
  for (int jo = 0; jo < NK - 4; jo += 4) {
    KSLICE(0, "8", true, jo + 3);
    KSLICE(1, "8", true, jo + 4);
    KSLICE(2, "8", true, jo + 5);
    KSLICE(3, "8", true, jo + 6);
  }
  // tail group: j = 12 (stages kslice 15), 13, 14, 15
  KSLICE(0, "8", true,  15);
  KSLICE(1, "8", false, 0);
  KSLICE(2, "4", false, 0);
  KSLICE(3, "0", false, 0);
#undef KSLICE

  // epilogue: lane holds rows crow0+mt*16+l15, cols ccol0+nt*16+kq*4+{0..3}
  const long crow0 = arow0 + wm * 128;
  const long ccol0 = bcol0 + wn * 64 + kq * 4;
#pragma unroll
  for (int mt = 0; mt < 8; ++mt) {
    long row = crow0 + mt * 16 + l15;
#pragma unroll
    for (int nt = 0; nt < 4; ++nt) {
      long col = ccol0 + nt * 16;
      if (OUT_BF16) {
        union { unsigned long long u; unsigned short h[4]; } pk;
#pragma unroll
        for (int r = 0; r < 4; ++r) {
          bf16 hh = __float2bfloat16(acc[mt][nt][r]);
          pk.h[r] = *(unsigned short*)&hh;
        }
        __builtin_nontemporal_store(pk.u,
            (unsigned long long*)((bf16*)Cp + row * N + col));
      } else {
        f32x4 o = acc[mt][nt];
        if (BIAS) {
          o[0] += bias[col];     o[1] += bias[col + 1];
          o[2] += bias[col + 2]; o[3] += bias[col + 3];
        }
        __builtin_nontemporal_store(o, (f32x4*)((float*)Cp + row * N + col));
      }
    }
  }
}

// ---------------- kernel: windowed attention, one WG per (b, window p, head g) ------------
// qkv: [B][3136][1536] bf16 (cols: q 0-511 | k 512-1023 | v 1024-1535), head g slice = g*64
// rb : [8][49][49] fp32 ; outa: [B][3136][512] bf16
__global__ __launch_bounds__(256) void attn_win_kernel(
    const bf16* __restrict__ qkv, const float* __restrict__ rb, bf16* __restrict__ outa)
{
  __shared__ alignas(16) bf16 Qs[64 * 72];  // [token][chan], stride 72 (144B -> 2-way free)
  __shared__ alignas(16) bf16 Ks[64 * 72];
  __shared__ alignas(16) bf16 Vt[64 * 72];  // transposed: [chan][token]
  __shared__ alignas(16) bf16 Ps[64 * 72];  // probabilities [q][k]
  const int tid = threadIdx.x, lane = tid & 63, wid = tid >> 6;
  const int p = blockIdx.x, g = blockIdx.y, b = blockIdx.z;
  const int sh = p >> 3, sw = p & 7;
  const size_t nb = (size_t)b * NTOK;
  const int c8 = (tid & 7) * 8;

  // stage Q,K row-major + V transposed; zero-fill pad tokens 49..63
#pragma unroll
  for (int it = 0; it < 2; ++it) {
    int t = (tid >> 3) + it * 32;
    uint4 vq = {0, 0, 0, 0}, vk = vq, vv = vq;
    if (t < K49) {
      int ph = t / 7, pw = t - ph * 7;
      int n = (sh * 7 + ph) * WIM + sw * 7 + pw;
      const bf16* src = qkv + (nb + n) * 1536 + g * 64 + c8;
      vq = *(const uint4*)(src);
      vk = *(const uint4*)(src + 512);
      vv = *(const uint4*)(src + 1024);
    }
    *(uint4*)&Qs[t * 72 + c8] = vq;
    *(uint4*)&Ks[t * 72 + c8] = vk;
    union { uint4 u; unsigned short s[8]; } uv; uv.u = vv;
    unsigned short* vt16 = (unsigned short*)Vt;
#pragma unroll
    for (int e = 0; e < 8; ++e) vt16[(c8 + e) * 72 + t] = uv.s[e];
  }
  __syncthreads();

  const int l15 = lane & 15, kq = lane >> 4;
  // ---- S = Q K^T (wave w owns q rows 16w..16w+15; 4 col tiles) ----
  bf16x8 aq[2];
#pragma unroll
  for (int kk = 0; kk < 2; ++kk)
    aq[kk] = *(const bf16x8*)&Qs[(wid * 16 + l15) * 72 + kk * 32 + kq * 8];
  float sv[4][4];   // [ct][r]
#pragma unroll
  for (int ct = 0; ct < 4; ++ct) {
    f32x4 acc = {0.f, 0.f, 0.f, 0.f};
#pragma unroll
    for (int kk = 0; kk < 2; ++kk) {
      bf16x8 bk = *(const bf16x8*)&Ks[(ct * 16 + l15) * 72 + kk * 32 + kq * 8];
      acc = __builtin_amdgcn_mfma_f32_16x16x32_bf16(aq[kk], bk, acc, 0, 0, 0);
    }
    int kcol = ct * 16 + l15;
#pragma unroll
    for (int r = 0; r < 4; ++r) {
      int q = wid * 16 + kq * 4 + r;
      float bias = (q < K49 && kcol < K49) ? rb[((size_t)g * K49 + q) * K49 + kcol] : 0.f;
      float v = (acc[r] + bias) * 0.125f;          // (S + rel_bias) * dh^-0.5
      sv[ct][r] = (kcol < K49) ? v : -1e30f;       // mask pad keys
    }
  }
  // ---- softmax over keys (row q lives in the 16 lanes sharing kq) ----
#pragma unroll
  for (int r = 0; r < 4; ++r) {
    float m = fmaxf(fmaxf(sv[0][r], sv[1][r]), fmaxf(sv[2][r], sv[3][r]));
#pragma unroll
    for (int d = 1; d < 16; d <<= 1) m = fmaxf(m, __shfl_xor(m, d));
    float e0 = __expf(sv[0][r] - m), e1 = __expf(sv[1][r] - m);
    float e2 = __expf(sv[2][r] - m), e3 = __expf(sv[3][r] - m);
    float s = e0 + e1 + e2 + e3;
#pragma unroll
    for (int d = 1; d < 16; d <<= 1) s += __shfl_xor(s, d);
    float inv = 1.0f / s;
    int q = wid * 16 + kq * 4 + r;
    Ps[q * 72 +  0 + l15] = __float2bfloat16(e0 * inv);
    Ps[q * 72 + 16 + l15] = __float2bfloat16(e1 * inv);
    Ps[q * 72 + 32 + l15] = __float2bfloat16(e2 * inv);
    Ps[q * 72 + 48 + l15] = __float2bfloat16(e3 * inv);
  }
  __syncthreads();
  // ---- O = P V ----
  bf16x8 ap[2];
#pragma unroll
  for (int kk = 0; kk < 2; ++kk)
    ap[kk] = *(const bf16x8*)&Ps[(wid * 16 + l15) * 72 + kk * 32 + kq * 8];
#pragma unroll
  for (int ct = 0; ct < 4; ++ct) {
    f32x4 acc = {0.f, 0.f, 0.f, 0.f};
#pragma unroll
    for (int kk = 0; kk < 2; ++kk) {
      bf16x8 bv = *(const bf16x8*)&Vt[(ct * 16 + l15) * 72 + kk * 32 + kq * 8];
      acc = __builtin_amdgcn_mfma_f32_16x16x32_bf16(ap[kk], bv, acc, 0, 0, 0);
    }
#pragma unroll
    for (int r = 0; r < 4; ++r) {
      int q = wid * 16 + kq * 4 + r;
      if (q < K49) {
        int ph = q / 7, pw = q - ph * 7;
        int n = (sh * 7 + ph) * WIM + sw * 7 + pw;
        outa[(nb + n) * HD + g * 64 + ct * 16 + l15] = __float2bfloat16(acc[r]);
      }
    }
  }
}

// ---------------- launch ----------------
extern "C" void kernel_launch(void* const* d_in, const int* in_sizes, int n_in,
                              void* d_out, int out_size, void* d_ws, size_t ws_size,
                              hipStream_t stream) {
  (void)in_sizes; (void)n_in; (void)out_size;
  const float* x     = (const float*)d_in[0];
  // d_in[1] = mask: all-False with zero padding (56 % 7 == 0) -> no-op, skipped
  const float* wqkv  = (const float*)d_in[2];
  const float* wproj = (const float*)d_in[3];
  const float* bproj = (const float*)d_in[4];
  const float* rb    = (const float*)d_in[5];
  // d_in[6], d_in[7] = H, W (56, 56) constants

  // workspace layout (207,618,048 bytes total)
  char* ws = (char*)d_ws;
  bf16* x_bf    = (bf16*)(ws);              // 51,380,224 B ; reused as attnout after GEMM1
  bf16* wqkv_t  = (bf16*)(ws + 51380224);   //  1,572,864 B
  bf16* wproj_t = (bf16*)(ws + 52953088);   //    524,288 B
  bf16* qkv     = (bf16*)(ws + 53477376);   // 154,140,672 B
  bf16* attno   = x_bf;
  float* out    = (float*)d_out;
  if (ws_size < 207618048) return;  // fail visibly rather than corrupt

  cvt_x_kernel<<<dim3(12544), 256, 0, stream>>>(x, x_bf);                       // 50176*512/8/256
  cvt_transpose_kernel<<<dim3(3072), 256, 0, stream>>>(wqkv, wqkv_t, 512, 1536);
  cvt_transpose_kernel<<<dim3(1024), 256, 0, stream>>>(wproj, wproj_t, 512, 512);
  // GEMM1: 196 M-tiles x 6 N-tiles = 1176 blocks (1176 % 8 == 0)
  gemm256_kernel<1536, true, false><<<dim3(1176), 512, 0, stream>>>(
      x_bf, wqkv_t, (void*)qkv, nullptr, 6);
  attn_win_kernel<<<dim3(64, NHEAD, B_), 256, 0, stream>>>(qkv, rb, attno);
  // GEMM2: 196 x 2 = 392 blocks (392 % 8 == 0)
  gemm256_kernel<512, false, true><<<dim3(392), 512, 0, stream>>>(
      attno, wproj_t, (void*)out, bproj, 2);
}